// Round 4
// baseline (319.992 us; speedup 1.0000x reference)
//
#include <hip/hip_runtime.h>
#include <hip/hip_bf16.h>

constexpr int NN = 100000;
constexpr int NE = 625000;
constexpr int F  = 128;
constexpr int C  = 32;
constexpr int CQ  = C / 4;  // 8 float4 per projected row
constexpr int NB  = (NN + 255) / 256;   // 391 scan blocks

// ---------- degree / norm ----------
__global__ void k_zero(int* __restrict__ cnt) {
    int i = blockIdx.x * blockDim.x + threadIdx.x;
    if (i < NN) cnt[i] = 0;
}

__global__ void k_count(const int* __restrict__ dstA, int* __restrict__ cnt) {
    int e = blockIdx.x * blockDim.x + threadIdx.x;
    if (e < NE) atomicAdd(&cnt[dstA[e]], 1);
}

__global__ void k_dinv(const int* __restrict__ cnt, float* __restrict__ dinv) {
    int i = blockIdx.x * blockDim.x + threadIdx.x;
    if (i < NN) dinv[i] = rsqrtf((float)(cnt[i] + 1));   // +1 self loop
}

// ---------- CSR build: two-level scan ----------
__global__ __launch_bounds__(256) void k_blocksum(const int* __restrict__ cnt,
                                                  int* __restrict__ blocksums) {
    int idx = blockIdx.x * 256 + threadIdx.x;
    int v = (idx < NN) ? cnt[idx] : 0;
    #pragma unroll
    for (int off = 32; off; off >>= 1) v += __shfl_down(v, off, 64);
    __shared__ int ws[4];
    int lane = threadIdx.x & 63, wid = threadIdx.x >> 6;
    if (lane == 0) ws[wid] = v;
    __syncthreads();
    if (threadIdx.x == 0)
        blocksums[blockIdx.x] = ws[0] + ws[1] + ws[2] + ws[3];
}

__global__ __launch_bounds__(512) void k_scanB(const int* __restrict__ blocksums,
                                               int* __restrict__ blockoff,
                                               int* __restrict__ rowptr) {
    __shared__ int s[512];
    int t = threadIdx.x;
    s[t] = (t < NB) ? blocksums[t] : 0;
    __syncthreads();
    for (int off = 1; off < 512; off <<= 1) {
        int v = (t >= off) ? s[t - off] : 0;
        __syncthreads();
        s[t] += v;
        __syncthreads();
    }
    if (t < NB) blockoff[t] = (t == 0) ? 0 : s[t - 1];
    if (t == NB - 1) rowptr[NN] = s[t];
}

__global__ __launch_bounds__(256) void k_scanC(const int* __restrict__ cnt,
                                               const int* __restrict__ blockoff,
                                               int* __restrict__ rowptr,
                                               int* __restrict__ cursor) {
    __shared__ int s[256];
    int t = threadIdx.x;
    int idx = blockIdx.x * 256 + t;
    int val = (idx < NN) ? cnt[idx] : 0;
    s[t] = val;
    __syncthreads();
    for (int off = 1; off < 256; off <<= 1) {
        int v = (t >= off) ? s[t - off] : 0;
        __syncthreads();
        s[t] += v;
        __syncthreads();
    }
    if (idx < NN) {
        int r = blockoff[blockIdx.x] + s[t] - val;
        rowptr[idx] = r;
        cursor[idx] = r;
    }
}

__global__ void k_fill(const int* __restrict__ srcA, const int* __restrict__ dstA,
                       const float* __restrict__ dinv, int* __restrict__ cursor,
                       int* __restrict__ col, float* __restrict__ wgt) {
    int e = blockIdx.x * blockDim.x + threadIdx.x;
    if (e >= NE) return;
    int s = srcA[e], d = dstA[e];
    int pos = atomicAdd(&cursor[d], 1);
    col[pos] = s;
    wgt[pos] = dinv[s] * dinv[d];
}

// ---------- projection: z = x @ W^T, thread = (node, class-quad) ----------
// 400k threads -> ~24 waves/CU. W stays in L1 (16 KB); no LDS, no syncthreads.
__global__ __launch_bounds__(256) void k_proj(const float* __restrict__ x,
                                              const float* __restrict__ W,
                                              float* __restrict__ z) {
    int t = blockIdx.x * 256 + threadIdx.x;
    if (t >= NN * 4) return;
    int node = t >> 2;
    int qr   = t & 3;          // class-quad: classes [qr*8, qr*8+8)

    const float4* xr = (const float4*)(x + (size_t)node * F);     // 32 float4
    const float4* Wr = (const float4*)(W + (size_t)qr * 8 * F);   // 8 rows x 32 float4

    float acc[8];
    #pragma unroll
    for (int c = 0; c < 8; ++c) acc[c] = 0.f;

    #pragma unroll 4
    for (int q = 0; q < F / 4; ++q) {
        float4 xv = xr[q];     // 4 lanes of same node share address -> merged
        #pragma unroll
        for (int c = 0; c < 8; ++c) {
            float4 wv = Wr[c * (F / 4) + q];   // L1-resident
            acc[c] += xv.x * wv.x + xv.y * wv.y + xv.z * wv.z + xv.w * wv.w;
        }
    }
    float4* zp = (float4*)(z + (size_t)node * C + qr * 8);
    zp[0] = make_float4(acc[0], acc[1], acc[2], acc[3]);
    zp[1] = make_float4(acc[4], acc[5], acc[6], acc[7]);
}

// ---------- hop 1 (gather): z1[i] = dinv[i]^2*z0[i] + sum_e w*z0[col] ----------
__global__ void k_gather(const float* __restrict__ zin, const int* __restrict__ rowptr,
                         const int* __restrict__ col, const float* __restrict__ wgt,
                         const float* __restrict__ dinv, float* __restrict__ zout) {
    int t = blockIdx.x * blockDim.x + threadIdx.x;   // thread per (node, float4 chunk)
    if (t >= NN * CQ) return;
    int node = t >> 3;   // CQ = 8
    int q    = t & 7;
    float dn = dinv[node];
    float4 v = ((const float4*)zin)[node * CQ + q];
    float c  = dn * dn;
    float ax = c * v.x, ay = c * v.y, az = c * v.z, aw = c * v.w;
    int e0 = rowptr[node], e1 = rowptr[node + 1];
    for (int e = e0; e < e1; ++e) {
        int   s = col[e];
        float w = wgt[e];
        float4 u = ((const float4*)zin)[s * CQ + q];
        ax += w * u.x; ay += w * u.y; az += w * u.z; aw += w * u.w;
    }
    ((float4*)zout)[node * CQ + q] = make_float4(ax, ay, az, aw);
}

// ---------- hop 2 + bias + log_softmax, thread = (node, class-quad) ----------
__global__ __launch_bounds__(256) void k_hop2_finish(const float* __restrict__ zin,
                                                     const int* __restrict__ rowptr,
                                                     const int* __restrict__ col,
                                                     const float* __restrict__ wgt,
                                                     const float* __restrict__ dinv,
                                                     const float* __restrict__ b,
                                                     float* __restrict__ out) {
    int t = blockIdx.x * 256 + threadIdx.x;
    if (t >= NN * 4) return;
    int node = t >> 2;
    int qr   = t & 3;          // classes [qr*8, qr*8+8)

    float dn = dinv[node];
    float cc = dn * dn;
    const float4* zrow = (const float4*)(zin + (size_t)node * C) + qr * 2;
    float4 a0 = zrow[0], a1 = zrow[1];
    a0.x *= cc; a0.y *= cc; a0.z *= cc; a0.w *= cc;
    a1.x *= cc; a1.y *= cc; a1.z *= cc; a1.w *= cc;

    int e0 = rowptr[node], e1 = rowptr[node + 1];
    for (int e = e0; e < e1; ++e) {
        int   s = col[e];           // 4 lanes same address -> broadcast
        float w = wgt[e];
        const float4* u = (const float4*)(zin + (size_t)s * C) + qr * 2;
        float4 u0 = u[0], u1 = u[1];
        a0.x += w * u0.x; a0.y += w * u0.y; a0.z += w * u0.z; a0.w += w * u0.w;
        a1.x += w * u1.x; a1.y += w * u1.y; a1.z += w * u1.z; a1.w += w * u1.w;
    }

    float4 b0 = ((const float4*)b)[qr * 2];
    float4 b1 = ((const float4*)b)[qr * 2 + 1];
    float v[8] = { a0.x + b0.x, a0.y + b0.y, a0.z + b0.z, a0.w + b0.w,
                   a1.x + b1.x, a1.y + b1.y, a1.z + b1.z, a1.w + b1.w };

    float m = v[0];
    #pragma unroll
    for (int c = 1; c < 8; ++c) m = fmaxf(m, v[c]);
    m = fmaxf(m, __shfl_xor(m, 1, 64));     // reduce across the node's 4 lanes
    m = fmaxf(m, __shfl_xor(m, 2, 64));
    float s = 0.f;
    #pragma unroll
    for (int c = 0; c < 8; ++c) s += expf(v[c] - m);
    s += __shfl_xor(s, 1, 64);
    s += __shfl_xor(s, 2, 64);
    float lse = m + logf(s);

    float4* op = (float4*)(out + (size_t)node * C + qr * 8);
    op[0] = make_float4(v[0]-lse, v[1]-lse, v[2]-lse, v[3]-lse);
    op[1] = make_float4(v[4]-lse, v[5]-lse, v[6]-lse, v[7]-lse);
}

extern "C" void kernel_launch(void* const* d_in, const int* in_sizes, int n_in,
                              void* d_out, int out_size, void* d_ws, size_t ws_size,
                              hipStream_t stream) {
    const float* x  = (const float*)d_in[0];
    const int*   ei = (const int*)d_in[1];     // [2, NE] int32
    const float* W  = (const float*)d_in[2];
    const float* b  = (const float*)d_in[3];
    float* out = (float*)d_out;

    const int* srcA = ei;
    const int* dstA = ei + NE;

    char* p = (char*)d_ws;
    auto alloc = [&](size_t bytes) { char* r = p; p += (bytes + 255) & ~(size_t)255; return r; };
    int*   cnt       = (int*)  alloc(sizeof(int) * NN);
    float* dinv      = (float*)alloc(sizeof(float) * NN);
    int*   rowptr    = (int*)  alloc(sizeof(int) * (NN + 1));
    int*   cursor    = (int*)  alloc(sizeof(int) * NN);
    int*   blocksums = (int*)  alloc(sizeof(int) * NB);
    int*   blockoff  = (int*)  alloc(sizeof(int) * NB);
    int*   col       = (int*)  alloc(sizeof(int) * NE);
    float* wgt       = (float*)alloc(sizeof(float) * NE);
    float* z0        = (float*)alloc(sizeof(float) * (size_t)NN * C);
    float* z1        = (float*)alloc(sizeof(float) * (size_t)NN * C);

    // norm + CSR build
    k_zero    <<<(NN + 255) / 256, 256, 0, stream>>>(cnt);
    k_count   <<<(NE + 255) / 256, 256, 0, stream>>>(dstA, cnt);
    k_dinv    <<<(NN + 255) / 256, 256, 0, stream>>>(cnt, dinv);
    k_blocksum<<<NB, 256, 0, stream>>>(cnt, blocksums);
    k_scanB   <<<1, 512, 0, stream>>>(blocksums, blockoff, rowptr);
    k_scanC   <<<NB, 256, 0, stream>>>(cnt, blockoff, rowptr, cursor);
    k_fill    <<<(NE + 255) / 256, 256, 0, stream>>>(srcA, dstA, dinv, cursor, col, wgt);

    // project first (propagation commutes with the linear head)
    k_proj<<<(NN * 4 + 255) / 256, 256, 0, stream>>>(x, W, z0);

    // hop 1: z0 -> z1
    k_gather<<<(NN * CQ + 255) / 256, 256, 0, stream>>>(z0, rowptr, col, wgt, dinv, z1);
    // hop 2 fused with bias + log_softmax: z1 -> out
    k_hop2_finish<<<(NN * 4 + 255) / 256, 256, 0, stream>>>(z1, rowptr, col, wgt, dinv, b, out);
}

// Round 5
// 189.995 us; speedup vs baseline: 1.6842x; 1.6842x over previous
//
#include <hip/hip_runtime.h>
#include <hip/hip_bf16.h>

constexpr int NN = 100000;
constexpr int NE = 625000;
constexpr int F  = 128;
constexpr int C  = 32;
constexpr int CQ  = C / 4;  // 8 float4 per projected row
constexpr int NB  = (NN + 255) / 256;   // 391 scan blocks

// ---------- degree / norm ----------
__global__ void k_zero(int* __restrict__ cnt) {
    int i = blockIdx.x * blockDim.x + threadIdx.x;
    if (i < NN) cnt[i] = 0;
}

__global__ void k_count(const int* __restrict__ dstA, int* __restrict__ cnt) {
    int e = blockIdx.x * blockDim.x + threadIdx.x;
    if (e < NE) atomicAdd(&cnt[dstA[e]], 1);
}

__global__ void k_dinv(const int* __restrict__ cnt, float* __restrict__ dinv) {
    int i = blockIdx.x * blockDim.x + threadIdx.x;
    if (i < NN) dinv[i] = rsqrtf((float)(cnt[i] + 1));   // +1 self loop
}

// ---------- CSR build: two-level scan ----------
__global__ __launch_bounds__(256) void k_blocksum(const int* __restrict__ cnt,
                                                  int* __restrict__ blocksums) {
    int idx = blockIdx.x * 256 + threadIdx.x;
    int v = (idx < NN) ? cnt[idx] : 0;
    #pragma unroll
    for (int off = 32; off; off >>= 1) v += __shfl_down(v, off, 64);
    __shared__ int ws[4];
    int lane = threadIdx.x & 63, wid = threadIdx.x >> 6;
    if (lane == 0) ws[wid] = v;
    __syncthreads();
    if (threadIdx.x == 0)
        blocksums[blockIdx.x] = ws[0] + ws[1] + ws[2] + ws[3];
}

__global__ __launch_bounds__(512) void k_scanB(const int* __restrict__ blocksums,
                                               int* __restrict__ blockoff,
                                               int* __restrict__ rowptr) {
    __shared__ int s[512];
    int t = threadIdx.x;
    s[t] = (t < NB) ? blocksums[t] : 0;
    __syncthreads();
    for (int off = 1; off < 512; off <<= 1) {
        int v = (t >= off) ? s[t - off] : 0;
        __syncthreads();
        s[t] += v;
        __syncthreads();
    }
    if (t < NB) blockoff[t] = (t == 0) ? 0 : s[t - 1];
    if (t == NB - 1) rowptr[NN] = s[t];
}

__global__ __launch_bounds__(256) void k_scanC(const int* __restrict__ cnt,
                                               const int* __restrict__ blockoff,
                                               int* __restrict__ rowptr,
                                               int* __restrict__ cursor) {
    __shared__ int s[256];
    int t = threadIdx.x;
    int idx = blockIdx.x * 256 + t;
    int val = (idx < NN) ? cnt[idx] : 0;
    s[t] = val;
    __syncthreads();
    for (int off = 1; off < 256; off <<= 1) {
        int v = (t >= off) ? s[t - off] : 0;
        __syncthreads();
        s[t] += v;
        __syncthreads();
    }
    if (idx < NN) {
        int r = blockoff[blockIdx.x] + s[t] - val;
        rowptr[idx] = r;
        cursor[idx] = r;
    }
}

__global__ void k_fill(const int* __restrict__ srcA, const int* __restrict__ dstA,
                       const float* __restrict__ dinv, int* __restrict__ cursor,
                       int* __restrict__ col, float* __restrict__ wgt) {
    int e = blockIdx.x * blockDim.x + threadIdx.x;
    if (e >= NE) return;
    int s = srcA[e], d = dstA[e];
    int pos = atomicAdd(&cursor[d], 1);
    col[pos] = s;
    wgt[pos] = dinv[s] * dinv[d];
}

// ---------- projection: z = x @ W^T ----------
// thread = (node-quad, class-quad): 4x4 output block in registers.
// Per k-step: 4 x-float4 + 4 W-float4 loads -> 64 FMAs (FMA:load = 8).
// 200k threads = 12 waves/CU; W (16 KB) L1-resident, 8 distinct addrs/load instr.
__global__ __launch_bounds__(256) void k_proj(const float* __restrict__ x,
                                              const float* __restrict__ W,
                                              float* __restrict__ z) {
    int t = blockIdx.x * 256 + threadIdx.x;
    if (t >= (NN / 4) * 8) return;
    int qr = t & 7;          // class-quad: classes [qr*4, qr*4+4)
    int nq = t >> 3;         // node-quad:  nodes   [nq*4, nq*4+4)
    int n0 = nq * 4;

    const float4* xr0 = (const float4*)(x + (size_t)(n0 + 0) * F);
    const float4* xr1 = (const float4*)(x + (size_t)(n0 + 1) * F);
    const float4* xr2 = (const float4*)(x + (size_t)(n0 + 2) * F);
    const float4* xr3 = (const float4*)(x + (size_t)(n0 + 3) * F);
    const float4* wr0 = (const float4*)(W + (size_t)(qr * 4 + 0) * F);
    const float4* wr1 = (const float4*)(W + (size_t)(qr * 4 + 1) * F);
    const float4* wr2 = (const float4*)(W + (size_t)(qr * 4 + 2) * F);
    const float4* wr3 = (const float4*)(W + (size_t)(qr * 4 + 3) * F);

    float acc[4][4];
    #pragma unroll
    for (int i = 0; i < 4; ++i)
        #pragma unroll
        for (int c = 0; c < 4; ++c) acc[i][c] = 0.f;

    #pragma unroll 2
    for (int kq = 0; kq < F / 4; ++kq) {
        float4 xv[4] = { xr0[kq], xr1[kq], xr2[kq], xr3[kq] };
        float4 wv[4] = { wr0[kq], wr1[kq], wr2[kq], wr3[kq] };
        #pragma unroll
        for (int i = 0; i < 4; ++i)
            #pragma unroll
            for (int c = 0; c < 4; ++c)
                acc[i][c] += xv[i].x * wv[c].x + xv[i].y * wv[c].y
                           + xv[i].z * wv[c].z + xv[i].w * wv[c].w;
    }

    #pragma unroll
    for (int i = 0; i < 4; ++i)
        ((float4*)(z + (size_t)(n0 + i) * C))[qr] =
            make_float4(acc[i][0], acc[i][1], acc[i][2], acc[i][3]);
}

// ---------- hop 1 (gather): z1[i] = dinv[i]^2*z0[i] + sum_e w*z0[col] ----------
__global__ void k_gather(const float* __restrict__ zin, const int* __restrict__ rowptr,
                         const int* __restrict__ col, const float* __restrict__ wgt,
                         const float* __restrict__ dinv, float* __restrict__ zout) {
    int t = blockIdx.x * blockDim.x + threadIdx.x;   // thread per (node, float4 chunk)
    if (t >= NN * CQ) return;
    int node = t >> 3;   // CQ = 8
    int q    = t & 7;
    float dn = dinv[node];
    float4 v = ((const float4*)zin)[node * CQ + q];
    float c  = dn * dn;
    float ax = c * v.x, ay = c * v.y, az = c * v.z, aw = c * v.w;
    int e0 = rowptr[node], e1 = rowptr[node + 1];
    for (int e = e0; e < e1; ++e) {
        int   s = col[e];
        float w = wgt[e];
        float4 u = ((const float4*)zin)[s * CQ + q];
        ax += w * u.x; ay += w * u.y; az += w * u.z; aw += w * u.w;
    }
    ((float4*)zout)[node * CQ + q] = make_float4(ax, ay, az, aw);
}

// ---------- hop 2 + bias + log_softmax, thread = (node, class-quad of 8) ----------
__global__ __launch_bounds__(256) void k_hop2_finish(const float* __restrict__ zin,
                                                     const int* __restrict__ rowptr,
                                                     const int* __restrict__ col,
                                                     const float* __restrict__ wgt,
                                                     const float* __restrict__ dinv,
                                                     const float* __restrict__ b,
                                                     float* __restrict__ out) {
    int t = blockIdx.x * 256 + threadIdx.x;
    if (t >= NN * 4) return;
    int node = t >> 2;
    int qr   = t & 3;          // classes [qr*8, qr*8+8)

    float dn = dinv[node];
    float cc = dn * dn;
    const float4* zrow = (const float4*)(zin + (size_t)node * C) + qr * 2;
    float4 a0 = zrow[0], a1 = zrow[1];
    a0.x *= cc; a0.y *= cc; a0.z *= cc; a0.w *= cc;
    a1.x *= cc; a1.y *= cc; a1.z *= cc; a1.w *= cc;

    int e0 = rowptr[node], e1 = rowptr[node + 1];
    for (int e = e0; e < e1; ++e) {
        int   s = col[e];           // 4 lanes same address -> broadcast
        float w = wgt[e];
        const float4* u = (const float4*)(zin + (size_t)s * C) + qr * 2;
        float4 u0 = u[0], u1 = u[1];
        a0.x += w * u0.x; a0.y += w * u0.y; a0.z += w * u0.z; a0.w += w * u0.w;
        a1.x += w * u1.x; a1.y += w * u1.y; a1.z += w * u1.z; a1.w += w * u1.w;
    }

    float4 b0 = ((const float4*)b)[qr * 2];
    float4 b1 = ((const float4*)b)[qr * 2 + 1];
    float v[8] = { a0.x + b0.x, a0.y + b0.y, a0.z + b0.z, a0.w + b0.w,
                   a1.x + b1.x, a1.y + b1.y, a1.z + b1.z, a1.w + b1.w };

    float m = v[0];
    #pragma unroll
    for (int c = 1; c < 8; ++c) m = fmaxf(m, v[c]);
    m = fmaxf(m, __shfl_xor(m, 1, 64));     // reduce across the node's 4 lanes
    m = fmaxf(m, __shfl_xor(m, 2, 64));
    float s = 0.f;
    #pragma unroll
    for (int c = 0; c < 8; ++c) s += expf(v[c] - m);
    s += __shfl_xor(s, 1, 64);
    s += __shfl_xor(s, 2, 64);
    float lse = m + logf(s);

    float4* op = (float4*)(out + (size_t)node * C + qr * 8);
    op[0] = make_float4(v[0]-lse, v[1]-lse, v[2]-lse, v[3]-lse);
    op[1] = make_float4(v[4]-lse, v[5]-lse, v[6]-lse, v[7]-lse);
}

extern "C" void kernel_launch(void* const* d_in, const int* in_sizes, int n_in,
                              void* d_out, int out_size, void* d_ws, size_t ws_size,
                              hipStream_t stream) {
    const float* x  = (const float*)d_in[0];
    const int*   ei = (const int*)d_in[1];     // [2, NE] int32
    const float* W  = (const float*)d_in[2];
    const float* b  = (const float*)d_in[3];
    float* out = (float*)d_out;

    const int* srcA = ei;
    const int* dstA = ei + NE;

    char* p = (char*)d_ws;
    auto alloc = [&](size_t bytes) { char* r = p; p += (bytes + 255) & ~(size_t)255; return r; };
    int*   cnt       = (int*)  alloc(sizeof(int) * NN);
    float* dinv      = (float*)alloc(sizeof(float) * NN);
    int*   rowptr    = (int*)  alloc(sizeof(int) * (NN + 1));
    int*   cursor    = (int*)  alloc(sizeof(int) * NN);
    int*   blocksums = (int*)  alloc(sizeof(int) * NB);
    int*   blockoff  = (int*)  alloc(sizeof(int) * NB);
    int*   col       = (int*)  alloc(sizeof(int) * NE);
    float* wgt       = (float*)alloc(sizeof(float) * NE);
    float* z0        = (float*)alloc(sizeof(float) * (size_t)NN * C);
    float* z1        = (float*)alloc(sizeof(float) * (size_t)NN * C);

    // norm + CSR build
    k_zero    <<<(NN + 255) / 256, 256, 0, stream>>>(cnt);
    k_count   <<<(NE + 255) / 256, 256, 0, stream>>>(dstA, cnt);
    k_dinv    <<<(NN + 255) / 256, 256, 0, stream>>>(cnt, dinv);
    k_blocksum<<<NB, 256, 0, stream>>>(cnt, blocksums);
    k_scanB   <<<1, 512, 0, stream>>>(blocksums, blockoff, rowptr);
    k_scanC   <<<NB, 256, 0, stream>>>(cnt, blockoff, rowptr, cursor);
    k_fill    <<<(NE + 255) / 256, 256, 0, stream>>>(srcA, dstA, dinv, cursor, col, wgt);

    // project first (propagation commutes with the linear head)
    k_proj<<<((NN / 4) * 8 + 255) / 256, 256, 0, stream>>>(x, W, z0);

    // hop 1: z0 -> z1
    k_gather<<<(NN * CQ + 255) / 256, 256, 0, stream>>>(z0, rowptr, col, wgt, dinv, z1);
    // hop 2 fused with bias + log_softmax: z1 -> out
    k_hop2_finish<<<(NN * 4 + 255) / 256, 256, 0, stream>>>(z1, rowptr, col, wgt, dinv, b, out);
}